// Round 5
// baseline (165.699 us; speedup 1.0000x reference)
//
#include <hip/hip_runtime.h>

#define EPS 1e-7f
#define T_DIM 2048
#define TP1   2049
#define H_DIM 8
#define B_DIM 8
#define SP    2080   // padded xT row length (bf16 elements), 16B-aligned rows
#define NFRAG 138    // A-fragment table entries per head: b0 = fb*16 - 32
#define FB_OFF 32
#define NJOBS 4096   // 64 combos x 64 strips of 32 rows

typedef short v8s __attribute__((ext_vector_type(8)));
typedef float v4f __attribute__((ext_vector_type(4)));

static __device__ __forceinline__ unsigned short f2bf(float f) {
  union { float f; unsigned u; } v; v.f = f;
  unsigned r = v.u + 0x7fffu + ((v.u >> 16) & 1u);  // RTNE
  return (unsigned short)(r >> 16);
}

#define J1_BLOCKS 276    // fragA: 8*138 frags * 64 lanes / 256
#define J2_BLOCKS 264    // transpose: 8 * 33
#define J3_BLOCKS 4098   // xhat (head H): 8*2049 rows / 4
#define J4_BLOCKS 64     // row t=2048 of heads 0..7: one block per (h,b)

// Fused prep: [J1] MFMA A-fragment table, [J2] x -> bf16 transpose,
// [J3] head-H output (single l2norm of xp), [J4] t=2048 row GEMV for heads 0..7.
__global__ __launch_bounds__(256) void prep(const float* __restrict__ x,
                                            const float* __restrict__ W,
                                            unsigned short* __restrict__ fragA,
                                            unsigned short* __restrict__ xT,
                                            float* __restrict__ out) {
  __shared__ float tile[64][65];
  __shared__ float red4[4][64];
  int bid = blockIdx.x;
  if (bid < J1_BLOCKS) {
    // fragA[((h*NFRAG+fb)*64+lane)*8]: A[m=lm][k=quad*8+j] = k_h[b0+lm-8q-j], b0=fb*16-32
    int tid = bid * 256 + threadIdx.x;
    int blk = tid >> 6, lane = tid & 63;
    int h = blk / NFRAG, fb = blk - h * NFRAG;
    int b0 = fb * 16 - FB_OFF;
    int lm = lane & 15, quad = lane >> 4;
    v8s frag;
    #pragma unroll
    for (int j = 0; j < 8; ++j) {
      int d = b0 + lm - 8 * quad - j;
      float v = 0.0f;
      if (d >= 0 && d < T_DIM) v = __expf(W[d * H_DIM + h]);
      else if (d == T_DIM) v = 1.0f;
      frag[j] = (short)f2bf(v);
    }
    *(v8s*)(fragA + (size_t)tid * 8) = frag;
    return;
  }
  bid -= J1_BLOCKS;
  if (bid < J2_BLOCKS) {
    int b = bid / 33, st = bid % 33;
    int tid = threadIdx.x;
    if (st == 32) {  // zero pad s in [2048, 2080)
      #pragma unroll
      for (int i = 0; i < 8; ++i) {
        int idx = tid * 8 + i;
        int dd = idx >> 5, sl = idx & 31;
        xT[((size_t)b * 64 + dd) * SP + T_DIM + sl] = 0;
      }
      return;
    }
    int s0 = st * 64;
    int c = tid & 63, r4 = tid >> 6;
    #pragma unroll
    for (int i = 0; i < 16; ++i) {
      int sl = r4 * 16 + i;
      tile[sl][c] = x[((size_t)b * T_DIM + (s0 + sl)) * 64 + c];
    }
    __syncthreads();
    #pragma unroll
    for (int i = 0; i < 16; ++i) {
      int dd = r4 * 16 + i;
      xT[((size_t)b * 64 + dd) * SP + s0 + c] = f2bf(tile[c][dd]);
    }
    return;
  }
  bid -= J2_BLOCKS;
  if (bid < J3_BLOCKS) {  // head H: single l2norm of xp
    int row = bid * 4 + (threadIdx.x >> 6);
    if (row >= B_DIM * TP1) return;
    int b = row / TP1, t = row - b * TP1;
    int dd = threadIdx.x & 63;
    float v = (t < T_DIM) ? x[((size_t)b * T_DIM + t) * 64 + dd] : 0.0f;
    float ss = v * v;
    ss += __shfl_xor(ss, 1);  ss += __shfl_xor(ss, 2);
    ss += __shfl_xor(ss, 4);  ss += __shfl_xor(ss, 8);
    ss += __shfl_xor(ss, 16); ss += __shfl_xor(ss, 32);
    float inv = 1.0f / (sqrtf(ss) + EPS);
    __builtin_nontemporal_store(v * inv,
        &out[(((size_t)(H_DIM * B_DIM + b) * TP1 + t) << 6) + dd]);
    return;
  }
  bid -= J3_BLOCKS;
  {  // J4: row t=2048 of head h: v = sum_s exp-kernel(2048-s) * x[b,s,:], double l2norm
    int h = bid >> 3, b = bid & 7;
    int dd = threadIdx.x & 63, c = threadIdx.x >> 6;
    float a = 0.0f;
    #pragma unroll 4
    for (int i = 0; i < 512; ++i) {
      int s = c * 512 + i;
      float k = (s == 0) ? 1.0f : __expf(W[(T_DIM - s) * H_DIM + h]);
      a = fmaf(k, x[((size_t)b * T_DIM + s) * 64 + dd], a);
    }
    red4[c][dd] = a;
    __syncthreads();
    if (threadIdx.x < 64) {
      float v = red4[0][dd] + red4[1][dd] + red4[2][dd] + red4[3][dd];
      float ss = v * v;
      ss += __shfl_xor(ss, 1);  ss += __shfl_xor(ss, 2);
      ss += __shfl_xor(ss, 4);  ss += __shfl_xor(ss, 8);
      ss += __shfl_xor(ss, 16); ss += __shfl_xor(ss, 32);
      float n1 = sqrtf(ss);
      float u  = n1 / (n1 + EPS);
      float inv = 1.0f / ((n1 + EPS) * (u + EPS));
      __builtin_nontemporal_store(v * inv,
          &out[(((size_t)(h * B_DIM + b) * TP1 + T_DIM) << 6) + dd]);
    }
  }
}

// Statically balanced Toeplitz GEMM. Job = (combo, strip of 32 t-rows); 4096 jobs.
// Wave gid does jobs {gid, 4095-gid} -> strips (63-g, g): exactly 65 K-steps per
// wave, identical for ALL waves -> every block uniform -> placement-proof balance.
// No LDS, no barriers, no K-split. Depth-1 double-buffered prefetch; nt stores.
__global__ __launch_bounds__(256) void toeplitz_mm(const unsigned short* __restrict__ fragA,
                                                   const unsigned short* __restrict__ xT,
                                                   float* __restrict__ out) {
  const int lane = threadIdx.x & 63;
  const int w    = threadIdx.x >> 6;
  const int lm   = lane & 15;
  const int quad = lane >> 4;
  const int gid  = blockIdx.x * 4 + w;

  #pragma unroll 1
  for (int job = 0; job < 2; ++job) {
    const int jj    = job ? (NJOBS - 1 - gid) : gid;
    const int strip = 63 - (jj >> 6);
    const int combo = jj & 63;
    const int h = combo & 7, b = combo >> 3;
    const int tw = strip * 32;

    const unsigned short* fA = fragA + ((size_t)h * NFRAG * 64 + lane) * 8;
    const unsigned short* xb = xT + ((size_t)b * 64 + lm) * SP + 8 * quad;
    const int s_last = tw;   // last s0 (inclusive), step 32

    v4f acc[2][4] = {};      // rows tw+16*mt+4*quad+r, cols 16*nt+lm
    v8s a0[2], a1[2], b0[4], b1[4];

#define LOAD_A(dst, s0v) do {                                                        \
    dst[0] = *(const v8s*)(fA + (size_t)((tw      - (s0v) + FB_OFF) >> 4) * 512);    \
    dst[1] = *(const v8s*)(fA + (size_t)((tw + 16 - (s0v) + FB_OFF) >> 4) * 512); } while (0)
#define LOAD_B(dst, s0v) do {                                        \
    const unsigned short* _p = xb + (s0v);                           \
    dst[0] = *(const v8s*)(_p);                                      \
    dst[1] = *(const v8s*)(_p + 16 * SP);                            \
    dst[2] = *(const v8s*)(_p + 32 * SP);                            \
    dst[3] = *(const v8s*)(_p + 48 * SP); } while (0)
#define DO_MFMA(fa, fb) do {                                         \
    _Pragma("unroll")                                                \
    for (int mt = 0; mt < 2; ++mt)                                   \
      _Pragma("unroll")                                              \
      for (int nt = 0; nt < 4; ++nt)                                 \
        acc[mt][nt] = __builtin_amdgcn_mfma_f32_16x16x32_bf16(fa[mt], fb[nt], acc[mt][nt], 0, 0, 0); } while (0)

    int s0 = 0;
    LOAD_A(a0, 0); LOAD_B(b0, 0);
    for (;;) {
      bool more = (s0 + 32 <= s_last);
      if (more) { LOAD_A(a1, s0 + 32); LOAD_B(b1, s0 + 32); }
      DO_MFMA(a0, b0);
      if (!more) break;
      s0 += 32;
      bool more2 = (s0 + 32 <= s_last);
      if (more2) { LOAD_A(a0, s0 + 32); LOAD_B(b0, s0 + 32); }
      DO_MFMA(a1, b1);
      if (!more2) break;
      s0 += 32;
    }

    // Epilogue: double l2-norm over dd (softmax Z cancels up to eps ~3e-7).
    // C/D layout: col = lane&15 (dd offset), row = quad*4 + reg. All rows t < 2048.
    #pragma unroll
    for (int mt = 0; mt < 2; ++mt) {
      #pragma unroll
      for (int r = 0; r < 4; ++r) {
        float ss = 0.0f;
        #pragma unroll
        for (int nt = 0; nt < 4; ++nt) { float a = acc[mt][nt][r]; ss += a * a; }
        ss += __shfl_xor(ss, 1);
        ss += __shfl_xor(ss, 2);
        ss += __shfl_xor(ss, 4);
        ss += __shfl_xor(ss, 8);
        int t = tw + 16 * mt + 4 * quad + r;
        float n1 = sqrtf(ss);
        float u  = n1 / (n1 + EPS);
        float inv = 1.0f / ((n1 + EPS) * (u + EPS));
        float* op = out + (((size_t)(h * B_DIM + b) * TP1 + t) << 6) + lm;
        #pragma unroll
        for (int nt = 0; nt < 4; ++nt)
          __builtin_nontemporal_store(acc[mt][nt][r] * inv, op + 16 * nt);
      }
    }
  }
#undef LOAD_A
#undef LOAD_B
#undef DO_MFMA
}

extern "C" void kernel_launch(void* const* d_in, const int* in_sizes, int n_in,
                              void* d_out, int out_size, void* d_ws, size_t ws_size,
                              hipStream_t stream) {
  const float* x = (const float*)d_in[0];   // [8, 2048, 64] fp32
  const float* W = (const float*)d_in[1];   // [2048, 8] fp32
  float* out = (float*)d_out;               // [9, 8, 2049, 64] fp32

  unsigned short* xT    = (unsigned short*)d_ws;                    // 8*64*2080*2 = 2,129,920 B
  unsigned short* fragA = (unsigned short*)((char*)d_ws + 2131968); // 8*138*64*8*2 = 1,130,496 B

  hipLaunchKernelGGL(prep, dim3(J1_BLOCKS + J2_BLOCKS + J3_BLOCKS + J4_BLOCKS), dim3(256),
                     0, stream, x, W, fragA, xT, out);
  hipLaunchKernelGGL(toeplitz_mm, dim3(128 * 4), dim3(256), 0, stream, fragA, xT, out);
}

// Round 6
// 115.715 us; speedup vs baseline: 1.4320x; 1.4320x over previous
//
#include <hip/hip_runtime.h>

#define EPS 1e-7f
#define T_DIM 2048
#define TP1   2049
#define H_DIM 8
#define B_DIM 8
#define SP    2080   // padded xT row length (bf16 elements), 16B-aligned rows
#define NFRAG 138    // A-fragment table entries per head: b0 = fb*16 - 32
#define FB_OFF 32

typedef short v8s __attribute__((ext_vector_type(8)));
typedef float v4f __attribute__((ext_vector_type(4)));

static __device__ __forceinline__ unsigned short f2bf(float f) {
  union { float f; unsigned u; } v; v.f = f;
  unsigned r = v.u + 0x7fffu + ((v.u >> 16) & 1u);  // RTNE
  return (unsigned short)(r >> 16);
}

#define J1_BLOCKS 276    // fragA: 8*138 frags * 64 lanes / 256
#define J2_BLOCKS 264    // transpose + head-H norm: 8 * 33

// Fused prep: [J1] MFMA A-fragment table; [J2] x -> bf16 transpose AND head-H
// output (single l2norm of xp) from the same x read -- x is read exactly once.
__global__ __launch_bounds__(256) void prep(const float* __restrict__ x,
                                            const float* __restrict__ W,
                                            unsigned short* __restrict__ fragA,
                                            unsigned short* __restrict__ xT,
                                            float* __restrict__ out) {
  __shared__ float tile[64][65];
  int bid = blockIdx.x;
  if (bid < J1_BLOCKS) {
    // fragA[((h*NFRAG+fb)*64+lane)*8]: A[m=lm][k=quad*8+j] = k_h[b0+lm-8q-j], b0=fb*16-32
    int tid = bid * 256 + threadIdx.x;
    int blk = tid >> 6, lane = tid & 63;
    int h = blk / NFRAG, fb = blk - h * NFRAG;
    int b0 = fb * 16 - FB_OFF;
    int lm = lane & 15, quad = lane >> 4;
    v8s frag;
    #pragma unroll
    for (int j = 0; j < 8; ++j) {
      int d = b0 + lm - 8 * quad - j;
      float v = 0.0f;
      if (d >= 0 && d < T_DIM) v = __expf(W[d * H_DIM + h]);
      else if (d == T_DIM) v = 1.0f;
      frag[j] = (short)f2bf(v);
    }
    *(v8s*)(fragA + (size_t)tid * 8) = frag;
    return;
  }
  bid -= J1_BLOCKS;
  {
    int b = bid / 33, st = bid % 33;
    int tid = threadIdx.x;
    if (st == 32) {  // zero pad s in [2048,2080); b==0 also zeroes head-H t=2048 rows
      #pragma unroll
      for (int i = 0; i < 8; ++i) {
        int idx = tid * 8 + i;
        int dd = idx >> 5, sl = idx & 31;
        xT[((size_t)b * 64 + dd) * SP + T_DIM + sl] = 0;
      }
      if (b == 0) {
        for (int i = tid; i < 512; i += 256)
          __builtin_nontemporal_store(0.0f,
            &out[(((size_t)(H_DIM * B_DIM + (i >> 6)) * TP1 + T_DIM) << 6) + (i & 63)]);
      }
      return;
    }
    int s0 = st * 64;
    int c = tid & 63, r4 = tid >> 6;
    #pragma unroll
    for (int i = 0; i < 16; ++i) {
      int sl = r4 * 16 + i;
      tile[sl][c] = x[((size_t)b * T_DIM + (s0 + sl)) * 64 + c];
    }
    __syncthreads();
    #pragma unroll
    for (int i = 0; i < 16; ++i) {
      int dd = r4 * 16 + i;
      xT[((size_t)b * 64 + dd) * SP + s0 + c] = f2bf(tile[c][dd]);
    }
    // head-H (single l2norm of x rows) from the LDS tile: wave r4 takes 16 rows
    #pragma unroll
    for (int i = 0; i < 16; ++i) {
      int row = r4 * 16 + i;
      float v = tile[row][c];
      float ss = v * v;
      ss += __shfl_xor(ss, 1);  ss += __shfl_xor(ss, 2);
      ss += __shfl_xor(ss, 4);  ss += __shfl_xor(ss, 8);
      ss += __shfl_xor(ss, 16); ss += __shfl_xor(ss, 32);
      float inv = 1.0f / (sqrtf(ss) + EPS);
      __builtin_nontemporal_store(v * inv,
          &out[(((size_t)(H_DIM * B_DIM + b) * TP1 + (s0 + row)) << 6) + c]);
    }
  }
}

// Toeplitz GEMM, M=64 rows per wave, depth-3 pipelined, shift-reuse A.
// Job j: strip = 32-(j>>6) (strip 32 = masked row-2048 strip), combo = j&63
// (4 consecutive jobs share b -> block's 4 waves share B lines in L1).
// A-frags: frag(mt,s+32)=frag(mt-2,s) => 2 new frags/step, 8 circular slots.
// Anti-gradient block rank pairing keeps per-CU work ~constant.
__global__ __launch_bounds__(256) void toeplitz_mm(const unsigned short* __restrict__ fragA,
                                                   const unsigned short* __restrict__ xT,
                                                   float* __restrict__ out) {
  const int lane = threadIdx.x & 63;
  const int w    = threadIdx.x >> 6;
  const int lm   = lane & 15;
  const int quad = lane >> 4;

  const int bi   = blockIdx.x;
  const int rank = (bi < 256) ? bi : (bi < 512 ? 767 - bi : bi);
  const int j    = rank * 4 + w;
  const int strip = 32 - (j >> 6);
  const int combo = j & 63;
  const int h = combo & 7, b = combo >> 3;
  const int tw = strip * 64;

  const unsigned short* fA = fragA + ((size_t)h * NFRAG * 64 + lane) * 8;
  const unsigned short* xb = xT + ((size_t)b * 64 + lm) * SP + 8 * quad;
  const int s_last = min(tw + 32, T_DIM);      // last s0, inclusive
  const int fbase  = (tw + FB_OFF) >> 4;

  v4f acc[4][4] = {};   // rows tw+16*mt+4*quad+r, cols 16*nt+lm
  v8s As[8];            // circular: slot[(mt-2p)&7] holds frag(mt, step p)
  v8s Bs[4][4];         // 4-step rotation

#define SLOT(mt, P) (((mt) + 16 - 2 * (P)) & 7)
#define LOAD_B(dst, sv) do {                                         \
    const unsigned short* _p = xb + (sv);                            \
    dst[0] = *(const v8s*)(_p);                                      \
    dst[1] = *(const v8s*)(_p + 16 * SP);                            \
    dst[2] = *(const v8s*)(_p + 32 * SP);                            \
    dst[3] = *(const v8s*)(_p + 48 * SP); } while (0)

  // Prologue: fill all 8 A slots (covers steps 0..2 exactly), 3 B buffers.
  #pragma unroll
  for (int k = 0; k < 8; ++k) {
    int fb = fbase + ((k + 4) & 7) - 4;
    if (fb < 0) fb = 0;                 // clamped -> garbage for nonexistent steps
    As[k] = *(const v8s*)(fA + (size_t)fb * 512);
  }
  LOAD_B(Bs[0], 0);
  { int s1 = min(32, s_last); LOAD_B(Bs[1], s1); }
  { int s2 = min(64, s_last); LOAD_B(Bs[2], s2); }

  int s0 = 0;

#define PHASE(P) {                                                            \
    { const v8s* _bq = Bs[(P) & 3];                                           \
      _Pragma("unroll")                                                       \
      for (int nt = 0; nt < 4; ++nt) {                                        \
        acc[0][nt] = __builtin_amdgcn_mfma_f32_16x16x32_bf16(As[SLOT(0,P)], _bq[nt], acc[0][nt], 0, 0, 0); \
        acc[1][nt] = __builtin_amdgcn_mfma_f32_16x16x32_bf16(As[SLOT(1,P)], _bq[nt], acc[1][nt], 0, 0, 0); \
        acc[2][nt] = __builtin_amdgcn_mfma_f32_16x16x32_bf16(As[SLOT(2,P)], _bq[nt], acc[2][nt], 0, 0, 0); \
        acc[3][nt] = __builtin_amdgcn_mfma_f32_16x16x32_bf16(As[SLOT(3,P)], _bq[nt], acc[3][nt], 0, 0, 0); \
      } }                                                                     \
    if (s0 == s_last) goto done;                                              \
    { int _fb = (tw - s0 - 64) >> 4;          /* frag(0, p+3) */              \
      int _f0 = _fb > 0 ? _fb : 0;                                            \
      int _f1 = (_fb + 1) > 0 ? (_fb + 1) : 0;                                \
      As[SLOT(0, (P) + 3)] = *(const v8s*)(fA + (size_t)_f0 * 512);           \
      As[SLOT(1, (P) + 3)] = *(const v8s*)(fA + (size_t)_f1 * 512);           \
      int _sp = s0 + 96; if (_sp > s_last) _sp = s_last;                      \
      LOAD_B(Bs[((P) + 3) & 3], _sp); }                                       \
    s0 += 32; }

  for (;;) { PHASE(0) PHASE(1) PHASE(2) PHASE(3) }
done:

  // Epilogue: double l2-norm over dd (softmax Z cancels up to eps ~3e-7).
  // C/D layout: col = lane&15, row = quad*4 + reg. Mask t<=2048 (strip 32).
  #pragma unroll
  for (int mt = 0; mt < 4; ++mt) {
    #pragma unroll
    for (int r = 0; r < 4; ++r) {
      float ss = 0.0f;
      #pragma unroll
      for (int nt = 0; nt < 4; ++nt) { float a = acc[mt][nt][r]; ss += a * a; }
      ss += __shfl_xor(ss, 1);
      ss += __shfl_xor(ss, 2);
      ss += __shfl_xor(ss, 4);
      ss += __shfl_xor(ss, 8);
      int t = tw + 16 * mt + 4 * quad + r;
      if (t <= T_DIM) {
        float n1 = sqrtf(ss);
        float u  = n1 / (n1 + EPS);
        float inv = 1.0f / ((n1 + EPS) * (u + EPS));
        float* op = out + (((size_t)(h * B_DIM + b) * TP1 + t) << 6) + lm;
        #pragma unroll
        for (int nt = 0; nt < 4; ++nt)
          __builtin_nontemporal_store(acc[mt][nt][r] * inv, op + 16 * nt);
      }
    }
  }
#undef PHASE
#undef LOAD_B
#undef SLOT
}

extern "C" void kernel_launch(void* const* d_in, const int* in_sizes, int n_in,
                              void* d_out, int out_size, void* d_ws, size_t ws_size,
                              hipStream_t stream) {
  const float* x = (const float*)d_in[0];   // [8, 2048, 64] fp32
  const float* W = (const float*)d_in[1];   // [2048, 8] fp32
  float* out = (float*)d_out;               // [9, 8, 2049, 64] fp32

  unsigned short* xT    = (unsigned short*)d_ws;                    // 8*64*2080*2 = 2,129,920 B
  unsigned short* fragA = (unsigned short*)((char*)d_ws + 2131968); // 8*138*64*8*2 = 1,130,496 B

  hipLaunchKernelGGL(prep, dim3(J1_BLOCKS + J2_BLOCKS), dim3(256), 0, stream,
                     x, W, fragA, xT, out);
  hipLaunchKernelGGL(toeplitz_mm, dim3(528), dim3(256), 0, stream, fragA, xT, out);
}